// Round 7
// baseline (798.261 us; speedup 1.0000x reference)
//
#include <hip/hip_runtime.h>

#define HDIM 128
#define SEQ  14
#define G4   512
#define TLEN 8
#define NTHR 256

typedef _Float16 half8 __attribute__((ext_vector_type(8)));
typedef float f32x4 __attribute__((ext_vector_type(4)));

__device__ __forceinline__ float frcp_(float x) { return __builtin_amdgcn_rcpf(x); }
__device__ __forceinline__ float fsig_(float x) { return frcp_(1.0f + __expf(-x)); }
__device__ __forceinline__ float ftanh_(float x) {
    return 1.0f - 2.0f * frcp_(__expf(2.0f * x) + 1.0f);
}

struct __align__(16) SMem {
    _Float16 wdl[4][2][4][64][8];   // Wd B-fragments per (wave,grp,kt,lane): 32 KB
    _Float16 hbuf[2][HDIM];         // double-buffered h (f16)
    _Float16 ench[SEQ][HDIM];       // encoder outputs
    _Float16 encWe[SEQ][HDIM];      // enc_out @ We
    _Float16 hWdh[HDIM];            // h @ Wd
    float ctxF[HDIM + 4];           // context; [128] = x
    float inp[SEQ];
    float attnw[SEQ];
    float asum[SEQ];
    float score[SEQ];
    float wv[HDIM];
    float wf[HDIM];
};  // ~42.5 KB -> 2 blocks/CU fits 160 KB

// One block per batch element; 512 blocks -> 2 independent blocks per CU.
// Wave w owns gate-columns {32w+l, 32w+16+l} of all 4 gates. A-operand rows
// are ALL the same h vector (broadcast), so all MFMA D rows are identical:
// every lane holds its column's 4 gates in reg 0 -> zero cross-lane traffic.
__global__ __launch_bounds__(NTHR, 2) void seq2seq_kernel(
    const float* __restrict__ inputs,
    const float* __restrict__ Wih_e, const float* __restrict__ Whh_e, const float* __restrict__ b_e,
    const float* __restrict__ Wih_d, const float* __restrict__ Whh_d, const float* __restrict__ b_d,
    const float* __restrict__ We, const float* __restrict__ Wd,
    const float* __restrict__ Wv, const float* __restrict__ Wf, const float* __restrict__ bfp,
    float* __restrict__ out, int B)
{
    const int tid  = threadIdx.x;
    const int b    = blockIdx.x;
    const int w    = tid >> 6;
    const int lane = tid & 63;
    const int q    = lane >> 4;
    const int l    = lane & 15;
    const int grp  = q >> 1;               // 0: cols [32w,32w+16) ; 1: [32w+16,32w+32)
    const int mycol = 32 * w + 16 * grp + l;
    const bool writer = (q & 1) == 0;      // q0 writes grp0, q2 writes grp1
    __shared__ SMem S;

    // ---- one-time init ----
    if (tid < HDIM) {
        S.hbuf[0][tid] = (_Float16)0.0f;
        S.hbuf[1][tid] = (_Float16)0.0f;
        S.wv[tid] = Wv[tid];
        S.wf[tid] = Wf[tid];
    }
    if (tid < SEQ) { S.inp[tid] = inputs[b * SEQ + tid]; S.asum[tid] = 0.0f; }
    if (tid == 0) S.ctxF[HDIM] = inputs[b * SEQ + (SEQ - 1)];

    // Wd B-fragments -> LDS (each thread writes the frags it will later read)
    #pragma unroll
    for (int g2 = 0; g2 < 2; ++g2) {
        int col = 32 * w + 16 * g2 + l;
        #pragma unroll
        for (int kt = 0; kt < 4; ++kt)
            #pragma unroll
            for (int jj = 0; jj < 8; ++jj)
                S.wdl[w][g2][kt][lane][jj] = (_Float16)Wd[(32 * kt + 8 * q + jj) * HDIM + col];
    }

    // ---- encoder recurrent weights (B-frags) ----
    half8 whh[2][4][4];
    float wih[2][4], bia[2][4];
    #pragma unroll
    for (int g2 = 0; g2 < 2; ++g2)
        #pragma unroll
        for (int g = 0; g < 4; ++g) {
            int n = g * HDIM + 32 * w + 16 * g2 + l;
            wih[g2][g] = Wih_e[n];
            bia[g2][g] = b_e[n];
            #pragma unroll
            for (int kt = 0; kt < 4; ++kt) {
                half8 f;
                #pragma unroll
                for (int jj = 0; jj < 8; ++jj)
                    f[jj] = (_Float16)Whh_e[(32 * kt + 8 * q + jj) * G4 + n];
                whh[g2][g][kt] = f;
            }
        }
    float c = 0.0f;
    __syncthreads();

    int cur = 0;
    half8 af[4];
    float xs;
    {
        const _Float16* hr = &S.hbuf[0][0];
        #pragma unroll
        for (int kt = 0; kt < 4; ++kt) af[kt] = *(const half8*)&hr[32 * kt + 8 * q];
        xs = S.inp[0];
    }

    // ---- encoder: 14 steps, 1 barrier each ----
    for (int t = 0; t < SEQ; ++t) {
        f32x4 acc[2][4];
        #pragma unroll
        for (int g2 = 0; g2 < 2; ++g2)
            #pragma unroll
            for (int g = 0; g < 4; ++g) {
                float ci = fmaf(xs, wih[g2][g], bia[g2][g]);
                acc[g2][g] = (f32x4){ci, ci, ci, ci};
            }
        #pragma unroll
        for (int g2 = 0; g2 < 2; ++g2)
            #pragma unroll
            for (int g = 0; g < 4; ++g)
                #pragma unroll
                for (int kt = 0; kt < 4; ++kt)
                    acc[g2][g] = __builtin_amdgcn_mfma_f32_16x16x32_f16(af[kt], whh[g2][g][kt], acc[g2][g], 0, 0, 0);
        float v0 = grp ? acc[1][0][0] : acc[0][0][0];
        float v1 = grp ? acc[1][1][0] : acc[0][1][0];
        float v2 = grp ? acc[1][2][0] : acc[0][2][0];
        float v3 = grp ? acc[1][3][0] : acc[0][3][0];
        float ig = fsig_(v0), fg = fsig_(v1), gg = ftanh_(v2), og = fsig_(v3);
        c = fmaf(fg, c, ig * gg);
        float hn = og * ftanh_(c);
        int nxt = cur ^ 1;
        if (writer) {
            _Float16 hh = (_Float16)hn;
            S.hbuf[nxt][mycol] = hh;
            S.ench[t][mycol]   = hh;
        }
        __syncthreads();
        cur = nxt;
        if (t < SEQ - 1) {
            const _Float16* hr = &S.hbuf[cur][0];
            #pragma unroll
            for (int kt = 0; kt < 4; ++kt) af[kt] = *(const half8*)&hr[32 * kt + 8 * q];
            xs = S.inp[t + 1];
        }
    }

    // ---- encWe = enc_out @ We (one-time) ----
    {
        half8 wef[2][4];
        #pragma unroll
        for (int g2 = 0; g2 < 2; ++g2) {
            int n = 32 * w + 16 * g2 + l;
            #pragma unroll
            for (int kt = 0; kt < 4; ++kt) {
                half8 f;
                #pragma unroll
                for (int jj = 0; jj < 8; ++jj)
                    f[jj] = (_Float16)We[(32 * kt + 8 * q + jj) * HDIM + n];
                wef[g2][kt] = f;
            }
        }
        for (int t = 0; t < SEQ; ++t) {
            const _Float16* er = &S.ench[t][0];
            f32x4 a0 = {0.f, 0.f, 0.f, 0.f}, a1 = {0.f, 0.f, 0.f, 0.f};
            #pragma unroll
            for (int kt = 0; kt < 4; ++kt) {
                half8 a = *(const half8*)&er[32 * kt + 8 * q];
                a0 = __builtin_amdgcn_mfma_f32_16x16x32_f16(a, wef[0][kt], a0, 0, 0, 0);
                a1 = __builtin_amdgcn_mfma_f32_16x16x32_f16(a, wef[1][kt], a1, 0, 0, 0);
            }
            if (writer) S.encWe[t][mycol] = (_Float16)(grp ? a1[0] : a0[0]);
        }
    }

    // ---- decoder recurrent weights ----
    #pragma unroll
    for (int g2 = 0; g2 < 2; ++g2)
        #pragma unroll
        for (int g = 0; g < 4; ++g) {
            int n = g * HDIM + 32 * w + 16 * g2 + l;
            wih[g2][g] = Wih_d[n];
            bia[g2][g] = b_d[n];
            #pragma unroll
            for (int kt = 0; kt < 4; ++kt) {
                half8 f;
                #pragma unroll
                for (int jj = 0; jj < 8; ++jj)
                    f[jj] = (_Float16)Whh_d[(32 * kt + 8 * q + jj) * G4 + n];
                whh[g2][g][kt] = f;
            }
        }
    float bf0 = bfp[0];
    __syncthreads();   // encWe visible

    // ---- decoder: 8 steps ----
    for (int d = 0; d < TLEN; ++d) {
        // hWd = h @ Wd (B-frags from LDS)
        {
            const _Float16* hr = &S.hbuf[cur][0];
            f32x4 a0 = {0.f, 0.f, 0.f, 0.f}, a1 = {0.f, 0.f, 0.f, 0.f};
            #pragma unroll
            for (int kt = 0; kt < 4; ++kt) {
                half8 a  = *(const half8*)&hr[32 * kt + 8 * q];
                half8 b0 = *(const half8*)&S.wdl[w][0][kt][lane][0];
                half8 b1 = *(const half8*)&S.wdl[w][1][kt][lane][0];
                a0 = __builtin_amdgcn_mfma_f32_16x16x32_f16(a, b0, a0, 0, 0, 0);
                a1 = __builtin_amdgcn_mfma_f32_16x16x32_f16(a, b1, a1, 0, 0, 0);
            }
            if (writer) S.hWdh[mycol] = (_Float16)(grp ? a1[0] : a0[0]);
        }
        __syncthreads();
        // scores: (t, 16 lanes) x 8 j's
        if (tid < SEQ * 16) {
            int t = tid >> 4, sub = tid & 15;
            float s = 0.0f;
            #pragma unroll
            for (int i = 0; i < 8; ++i) {
                int j = sub * 8 + i;
                s = fmaf(ftanh_((float)S.encWe[t][j] + (float)S.hWdh[j]), S.wv[j], s);
            }
            s += __shfl_down(s, 8, 16);
            s += __shfl_down(s, 4, 16);
            s += __shfl_down(s, 2, 16);
            s += __shfl_down(s, 1, 16);
            if (sub == 0) S.score[t] = s;
        }
        __syncthreads();
        // softmax over 14
        if (tid == 0) {
            float sc[SEQ]; float mx = -1e30f;
            #pragma unroll
            for (int t = 0; t < SEQ; ++t) { sc[t] = S.score[t]; mx = fmaxf(mx, sc[t]); }
            float ssum = 0.0f;
            #pragma unroll
            for (int t = 0; t < SEQ; ++t) { float e = __expf(sc[t] - mx); sc[t] = e; ssum += e; }
            float inv = frcp_(ssum);
            #pragma unroll
            for (int t = 0; t < SEQ; ++t) {
                float a = sc[t] * inv;
                S.attnw[t] = a;
                S.asum[t] += a;
            }
        }
        __syncthreads();
        // context
        if (tid < HDIM) {
            float a = 0.0f;
            #pragma unroll
            for (int t = 0; t < SEQ; ++t)
                a = fmaf(S.attnw[t], (float)S.ench[t][tid], a);
            S.ctxF[tid] = a;
        }
        __syncthreads();
        // decoder LSTM: 129 steps
        {
            const _Float16* hr = &S.hbuf[cur][0];
            #pragma unroll
            for (int kt = 0; kt < 4; ++kt) af[kt] = *(const half8*)&hr[32 * kt + 8 * q];
            xs = S.ctxF[0];
        }
        for (int s = 0; s <= HDIM; ++s) {
            f32x4 acc[2][4];
            #pragma unroll
            for (int g2 = 0; g2 < 2; ++g2)
                #pragma unroll
                for (int g = 0; g < 4; ++g) {
                    float ci = fmaf(xs, wih[g2][g], bia[g2][g]);
                    acc[g2][g] = (f32x4){ci, ci, ci, ci};
                }
            #pragma unroll
            for (int g2 = 0; g2 < 2; ++g2)
                #pragma unroll
                for (int g = 0; g < 4; ++g)
                    #pragma unroll
                    for (int kt = 0; kt < 4; ++kt)
                        acc[g2][g] = __builtin_amdgcn_mfma_f32_16x16x32_f16(af[kt], whh[g2][g][kt], acc[g2][g], 0, 0, 0);
            float v0 = grp ? acc[1][0][0] : acc[0][0][0];
            float v1 = grp ? acc[1][1][0] : acc[0][1][0];
            float v2 = grp ? acc[1][2][0] : acc[0][2][0];
            float v3 = grp ? acc[1][3][0] : acc[0][3][0];
            float ig = fsig_(v0), fg = fsig_(v1), gg = ftanh_(v2), og = fsig_(v3);
            c = fmaf(fg, c, ig * gg);
            float hn = og * ftanh_(c);
            int nxt = cur ^ 1;
            if (writer) S.hbuf[nxt][mycol] = (_Float16)hn;
            __syncthreads();
            cur = nxt;
            if (s < HDIM) {
                const _Float16* hr = &S.hbuf[cur][0];
                #pragma unroll
                for (int kt = 0; kt < 4; ++kt) af[kt] = *(const half8*)&hr[32 * kt + 8 * q];
                xs = S.ctxF[s + 1];
            }
        }
        // output projection -> next x
        if (tid < 16) {
            half8 hv = *(const half8*)&S.hbuf[cur][tid * 8];
            float s = 0.0f;
            #pragma unroll
            for (int i = 0; i < 8; ++i) s = fmaf((float)hv[i], S.wf[tid * 8 + i], s);
            s += __shfl_down(s, 8, 16);
            s += __shfl_down(s, 4, 16);
            s += __shfl_down(s, 2, 16);
            s += __shfl_down(s, 1, 16);
            if (tid == 0) {
                float o = s + bf0;
                out[b * TLEN + d] = o;
                S.ctxF[HDIM] = o;
            }
        }
        __syncthreads();
    }

    // total_attn [B, 14, 1]
    if (tid < SEQ) out[B * TLEN + b * SEQ + tid] = S.asum[tid];
}

extern "C" void kernel_launch(void* const* d_in, const int* in_sizes, int n_in,
                              void* d_out, int out_size, void* d_ws, size_t ws_size,
                              hipStream_t stream) {
    const float* inputs = (const float*)d_in[0];
    const float* Wih_e = (const float*)d_in[2];
    const float* Whh_e = (const float*)d_in[3];
    const float* b_e   = (const float*)d_in[4];
    const float* Wih_d = (const float*)d_in[5];
    const float* Whh_d = (const float*)d_in[6];
    const float* b_d   = (const float*)d_in[7];
    const float* We    = (const float*)d_in[8];
    const float* Wd    = (const float*)d_in[9];
    const float* Wv    = (const float*)d_in[10];
    const float* Wf    = (const float*)d_in[11];
    const float* bfp   = (const float*)d_in[12];
    float* out = (float*)d_out;

    const int B = in_sizes[0] / SEQ;  // 512

    seq2seq_kernel<<<dim3(B), dim3(NTHR), 0, stream>>>(
        inputs, Wih_e, Whh_e, b_e, Wih_d, Whh_d, b_d, We, Wd, Wv, Wf, bfp, out, B);
}

// Round 8
// 709.576 us; speedup vs baseline: 1.1250x; 1.1250x over previous
//
#include <hip/hip_runtime.h>

#define HDIM 128
#define SEQ  14
#define G4   512
#define TLEN 8
#define NTHR 512
#define HROW 136   // hbuf row pitch in halves

typedef _Float16 half8 __attribute__((ext_vector_type(8)));
typedef float f32x4 __attribute__((ext_vector_type(4)));
typedef float f32x2 __attribute__((ext_vector_type(2)));

__device__ __forceinline__ float frcp_(float x) { return __builtin_amdgcn_rcpf(x); }
__device__ __forceinline__ float fsig_(float x) { return frcp_(1.0f + __expf(-x)); }
__device__ __forceinline__ float ftanh_(float x) {
    return 1.0f - 2.0f * frcp_(__expf(2.0f * x) + 1.0f);
}

struct __align__(16) SMem {
    _Float16 hbuf[2][16][HROW];            // h MFMA-A rows; rows 0,1 live
    _Float16 ench[SEQ][2][HDIM];           // encoder outputs
    _Float16 encWe[SEQ][2][HDIM];          // enc_out @ We
    _Float16 hWdh[2][HDIM];                // h @ Wd
    __align__(16) float ctx2[HDIM + 1][2]; // [s][e]; row 128 = x
    __align__(16) float inp2[SEQ][2];
    float attnw[2][SEQ];
    float asum[2][SEQ];
    float score[2][SEQ];
    float wv[HDIM];
    float wf[HDIM];
};

// One LSTM cell step for 2 batch elements (rows 0,1 of the MFMA tile).
// srcl = &hbuf[srcbuf][l][8q]; dstw = &hbuf[dstbuf][q][16w+l] (q<2 lanes store).
// Caller must __syncthreads() after.
__device__ __forceinline__ float lstm_core(
    const _Float16* __restrict__ srcl, _Float16* __restrict__ dstw, f32x2 xv,
    const half8 (&whh)[4][4], const float (&wih)[4], const float (&bia)[4],
    float& c, bool writer, int q)
{
    half8 a0 = *(const half8*)(srcl);
    half8 a1 = *(const half8*)(srcl + 32);
    half8 a2 = *(const half8*)(srcl + 64);
    half8 a3 = *(const half8*)(srcl + 96);
    f32x4 A[4], Bv[4];
    #pragma unroll
    for (int g = 0; g < 4; ++g) {
        float c0 = fmaf(xv[0], wih[g], bia[g]);
        float c1 = fmaf(xv[1], wih[g], bia[g]);
        A[g]  = (f32x4){c0, c1, c1, c1};
        Bv[g] = (f32x4){0.f, 0.f, 0.f, 0.f};
    }
    #pragma unroll
    for (int g = 0; g < 4; ++g) {
        A[g]  = __builtin_amdgcn_mfma_f32_16x16x32_f16(a0, whh[g][0], A[g],  0, 0, 0);
        Bv[g] = __builtin_amdgcn_mfma_f32_16x16x32_f16(a2, whh[g][2], Bv[g], 0, 0, 0);
        A[g]  = __builtin_amdgcn_mfma_f32_16x16x32_f16(a1, whh[g][1], A[g],  0, 0, 0);
        Bv[g] = __builtin_amdgcn_mfma_f32_16x16x32_f16(a3, whh[g][3], Bv[g], 0, 0, 0);
    }
    float v[4];
    #pragma unroll
    for (int g = 0; g < 4; ++g) {
        float e0 = A[g][0] + Bv[g][0];
        float e1 = A[g][1] + Bv[g][1];
        float sx = __shfl_xor(e1, 16, 64);
        v[g] = (q == 0) ? e0 : sx;
    }
    float ig = fsig_(v[0]), fg = fsig_(v[1]), gg = ftanh_(v[2]), og = fsig_(v[3]);
    c = fmaf(fg, c, ig * gg);
    float hn = og * ftanh_(c);
    if (writer) *dstw = (_Float16)hn;
    return hn;
}

__global__ __launch_bounds__(NTHR, 2) void seq2seq_kernel(
    const float* __restrict__ inputs,
    const float* __restrict__ Wih_e, const float* __restrict__ Whh_e, const float* __restrict__ b_e,
    const float* __restrict__ Wih_d, const float* __restrict__ Whh_d, const float* __restrict__ b_d,
    const float* __restrict__ We, const float* __restrict__ Wd,
    const float* __restrict__ Wv, const float* __restrict__ Wf, const float* __restrict__ bfp,
    float* __restrict__ out, int B)
{
    const int tid  = threadIdx.x;
    const int b0   = blockIdx.x * 2;
    const int w    = tid >> 6;
    const int lane = tid & 63;
    const int q    = lane >> 4;
    const int l    = lane & 15;
    const int wrcol = 16 * w + l;
    const bool writer = (q < 2);
    __shared__ SMem S;

    // lane-invariant LDS pointers (compile-time parity; no runtime `cur`)
    const _Float16* s0 = &S.hbuf[0][l][8 * q];
    const _Float16* s1 = &S.hbuf[1][l][8 * q];
    _Float16* d0 = &S.hbuf[0][q & 1][wrcol];
    _Float16* d1 = &S.hbuf[1][q & 1][wrcol];

    // ---- init ----
    if (tid < 2 * HDIM) {
        int e = tid >> 7, j = tid & 127;
        S.hbuf[0][e][j] = (_Float16)0.0f;
        S.hbuf[1][e][j] = (_Float16)0.0f;
    }
    if (tid < SEQ * 2) {
        int t = tid >> 1, m = tid & 1;
        S.inp2[t][m] = inputs[(b0 + m) * SEQ + t];
        S.asum[m][t] = 0.0f;
    }
    if (tid < HDIM) { S.wv[tid] = Wv[tid]; S.wf[tid] = Wf[tid]; }
    if (tid < 2) S.ctx2[HDIM][tid] = inputs[(b0 + tid) * SEQ + (SEQ - 1)];

    // ---- encoder weights (B-frags) ----
    half8 whh[4][4];
    float wih[4], bia[4];
    #pragma unroll
    for (int g = 0; g < 4; ++g) {
        int n = g * HDIM + wrcol;
        wih[g] = Wih_e[n];
        bia[g] = b_e[n];
        #pragma unroll
        for (int kt = 0; kt < 4; ++kt) {
            half8 f;
            #pragma unroll
            for (int jj = 0; jj < 8; ++jj)
                f[jj] = (_Float16)Whh_e[(32 * kt + 8 * q + jj) * G4 + n];
            whh[g][kt] = f;
        }
    }
    float c = 0.0f;
    __syncthreads();

    // ---- encoder: 14 steps (7 unrolled pairs, static parity) ----
    for (int t = 0; t < SEQ; t += 2) {
        f32x2 x0 = *(const f32x2*)&S.inp2[t][0];
        float hn = lstm_core(s0, d1, x0, whh, wih, bia, c, writer, q);
        if (writer) S.ench[t][q][wrcol] = (_Float16)hn;
        __syncthreads();
        f32x2 x1 = *(const f32x2*)&S.inp2[t + 1][0];
        hn = lstm_core(s1, d0, x1, whh, wih, bia, c, writer, q);
        if (writer) S.ench[t + 1][q][wrcol] = (_Float16)hn;
        __syncthreads();
    }
    // h now in hbuf[0]

    // ---- encWe = enc_out @ We (one-time) ----
    {
        half8 wef[4];
        #pragma unroll
        for (int kt = 0; kt < 4; ++kt) {
            half8 f;
            #pragma unroll
            for (int jj = 0; jj < 8; ++jj)
                f[jj] = (_Float16)We[(32 * kt + 8 * q + jj) * HDIM + wrcol];
            wef[kt] = f;
        }
        for (int t = 0; t < SEQ; ++t) {
            const _Float16* er = &S.ench[t][0][0] + l * HDIM;  // rows l>=2: defined garbage
            f32x4 dv = {0.f, 0.f, 0.f, 0.f};
            #pragma unroll
            for (int kt = 0; kt < 4; ++kt) {
                half8 a = *(const half8*)(er + 32 * kt + 8 * q);
                dv = __builtin_amdgcn_mfma_f32_16x16x32_f16(a, wef[kt], dv, 0, 0, 0);
            }
            if (q == 0) {
                S.encWe[t][0][wrcol] = (_Float16)dv[0];
                S.encWe[t][1][wrcol] = (_Float16)dv[1];
            }
        }
    }

    // ---- decoder weights ----
    half8 wdf[4];
    #pragma unroll
    for (int g = 0; g < 4; ++g) {
        int n = g * HDIM + wrcol;
        wih[g] = Wih_d[n];
        bia[g] = b_d[n];
        #pragma unroll
        for (int kt = 0; kt < 4; ++kt) {
            half8 f;
            #pragma unroll
            for (int jj = 0; jj < 8; ++jj)
                f[jj] = (_Float16)Whh_d[(32 * kt + 8 * q + jj) * G4 + n];
            whh[g][kt] = f;
        }
    }
    #pragma unroll
    for (int kt = 0; kt < 4; ++kt) {
        half8 f;
        #pragma unroll
        for (int jj = 0; jj < 8; ++jj)
            f[jj] = (_Float16)Wd[(32 * kt + 8 * q + jj) * HDIM + wrcol];
        wdf[kt] = f;
    }
    float bf0 = bfp[0];
    __syncthreads();   // encWe + x0 visible

    // ---- decoder: 8 steps, parity alternates (h enters in hbuf[0]) ----
    #pragma unroll 1
    for (int dd = 0; dd < TLEN; ++dd) {
        const bool even = (dd & 1) == 0;
        const _Float16* sC = even ? s0 : s1;
        const _Float16* sO = even ? s1 : s0;
        _Float16* dC = even ? d0 : d1;
        _Float16* dO = even ? d1 : d0;

        // hWd = h @ Wd
        {
            f32x4 dv = {0.f, 0.f, 0.f, 0.f};
            half8 a0 = *(const half8*)(sC);
            half8 a1 = *(const half8*)(sC + 32);
            half8 a2 = *(const half8*)(sC + 64);
            half8 a3 = *(const half8*)(sC + 96);
            dv = __builtin_amdgcn_mfma_f32_16x16x32_f16(a0, wdf[0], dv, 0, 0, 0);
            dv = __builtin_amdgcn_mfma_f32_16x16x32_f16(a1, wdf[1], dv, 0, 0, 0);
            dv = __builtin_amdgcn_mfma_f32_16x16x32_f16(a2, wdf[2], dv, 0, 0, 0);
            dv = __builtin_amdgcn_mfma_f32_16x16x32_f16(a3, wdf[3], dv, 0, 0, 0);
            if (q == 0) {
                S.hWdh[0][wrcol] = (_Float16)dv[0];
                S.hWdh[1][wrcol] = (_Float16)dv[1];
            }
        }
        __syncthreads();
        // scores
        if (tid < 2 * SEQ * 16) {
            int p = tid >> 4, sub = tid & 15;
            int m = p & 1, t = p >> 1;
            float s = 0.0f;
            #pragma unroll
            for (int i = 0; i < 8; ++i) {
                int j = sub * 8 + i;
                s = fmaf(ftanh_((float)S.encWe[t][m][j] + (float)S.hWdh[m][j]), S.wv[j], s);
            }
            s += __shfl_down(s, 8, 16);
            s += __shfl_down(s, 4, 16);
            s += __shfl_down(s, 2, 16);
            s += __shfl_down(s, 1, 16);
            if (sub == 0) S.score[m][t] = s;
        }
        __syncthreads();
        // softmax over 14 per element
        if (tid < 2) {
            int m = tid;
            float sc[SEQ]; float mx = -1e30f;
            #pragma unroll
            for (int t = 0; t < SEQ; ++t) { sc[t] = S.score[m][t]; mx = fmaxf(mx, sc[t]); }
            float ssum = 0.0f;
            #pragma unroll
            for (int t = 0; t < SEQ; ++t) { float e = __expf(sc[t] - mx); sc[t] = e; ssum += e; }
            float inv = frcp_(ssum);
            #pragma unroll
            for (int t = 0; t < SEQ; ++t) {
                float a = sc[t] * inv;
                S.attnw[m][t] = a;
                S.asum[m][t] += a;
            }
        }
        __syncthreads();
        // context -> ctx2[j][e]
        if (tid < 256) {
            int e = tid >> 7, j = tid & 127;
            float a = 0.0f;
            #pragma unroll
            for (int t = 0; t < SEQ; ++t)
                a = fmaf(S.attnw[e][t], (float)S.ench[t][e][j], a);
            S.ctx2[j][e] = a;
        }
        __syncthreads();

        // decoder LSTM: 129 steps = 64 static-parity pairs + 1
        const f32x2* xp = (const f32x2*)&S.ctx2[0][0];
        #pragma unroll 1
        for (int s2 = 0; s2 < 64; ++s2) {
            (void)lstm_core(sC, dO, xp[2 * s2], whh, wih, bia, c, writer, q);
            __syncthreads();
            (void)lstm_core(sO, dC, xp[2 * s2 + 1], whh, wih, bia, c, writer, q);
            __syncthreads();
        }
        (void)lstm_core(sC, dO, xp[HDIM], whh, wih, bia, c, writer, q);
        __syncthreads();
        // h now in the "other" buffer; output projection -> next x
        const _Float16* hO = even ? &S.hbuf[1][0][0] : &S.hbuf[0][0][0];
        if (tid < 32) {
            int m = tid >> 4, part = tid & 15;
            half8 hv = *(const half8*)(hO + m * HROW + part * 8);
            float s = 0.0f;
            #pragma unroll
            for (int i = 0; i < 8; ++i) s = fmaf((float)hv[i], S.wf[part * 8 + i], s);
            s += __shfl_down(s, 8, 16);
            s += __shfl_down(s, 4, 16);
            s += __shfl_down(s, 2, 16);
            s += __shfl_down(s, 1, 16);
            if (part == 0) {
                float o = s + bf0;
                out[(b0 + m) * TLEN + dd] = o;
                S.ctx2[HDIM][m] = o;
            }
        }
        __syncthreads();
    }

    // total_attn [B, 14, 1]
    if (tid < 2 * SEQ) {
        int m = tid / SEQ, t = tid % SEQ;
        out[B * TLEN + (b0 + m) * SEQ + t] = S.asum[m][t];
    }
}

extern "C" void kernel_launch(void* const* d_in, const int* in_sizes, int n_in,
                              void* d_out, int out_size, void* d_ws, size_t ws_size,
                              hipStream_t stream) {
    const float* inputs = (const float*)d_in[0];
    const float* Wih_e = (const float*)d_in[2];
    const float* Whh_e = (const float*)d_in[3];
    const float* b_e   = (const float*)d_in[4];
    const float* Wih_d = (const float*)d_in[5];
    const float* Whh_d = (const float*)d_in[6];
    const float* b_d   = (const float*)d_in[7];
    const float* We    = (const float*)d_in[8];
    const float* Wd    = (const float*)d_in[9];
    const float* Wv    = (const float*)d_in[10];
    const float* Wf    = (const float*)d_in[11];
    const float* bfp   = (const float*)d_in[12];
    float* out = (float*)d_out;

    const int B = in_sizes[0] / SEQ;  // 512

    seq2seq_kernel<<<dim3(B / 2), dim3(NTHR), 0, stream>>>(
        inputs, Wih_e, Whh_e, b_e, Wih_d, Whh_d, b_d, We, Wd, Wv, Wf, bfp, out, B);
}

// Round 9
// 642.982 us; speedup vs baseline: 1.2415x; 1.1036x over previous
//
#include <hip/hip_runtime.h>

#define HDIM 128
#define SEQ  14
#define G4   512
#define TLEN 8
#define NTHR 512

typedef _Float16 half8 __attribute__((ext_vector_type(8)));
typedef float f32x4 __attribute__((ext_vector_type(4)));
typedef float f32x2 __attribute__((ext_vector_type(2)));

__device__ __forceinline__ float frcp_(float x) { return __builtin_amdgcn_rcpf(x); }
__device__ __forceinline__ float fsig_(float x) { return frcp_(1.0f + __expf(-x)); }
__device__ __forceinline__ float ftanh_(float x) {
    return 1.0f - 2.0f * frcp_(__expf(2.0f * x) + 1.0f);
}

struct __align__(16) SMem {
    _Float16 h2[2][2][HDIM];               // [buf][elem][col] compact: broadcast A-reads
    _Float16 ench[SEQ][2][HDIM];           // encoder outputs
    _Float16 encWe[SEQ][2][HDIM];          // enc_out @ We
    _Float16 hWdh[2][HDIM];                // h @ Wd
    __align__(16) float ctx2[HDIM + 1][2]; // [s][e]; row 128 = x
    __align__(16) float inp2[SEQ][2];
    float attnw[2][SEQ];
    float asum[2][SEQ];
    float score[2][SEQ];
    float wv[HDIM];
    float wf[HDIM];
};  // ~18.5 KB

// One LSTM step for 2 batch elements. A-rows are read as h[elem = l&1], so
// MFMA D-rows alternate elements: in EVERY lane, reg0 = elem0's gate value
// and reg1 = elem1's -> no cross-lane motion at all; one cndmask per gate.
// Lane (q,l) of wave w activates elem (q&1), col 16w+l; q<2 lanes store.
// Caller must __syncthreads() after.
__device__ __forceinline__ float lstm_core(
    const _Float16* __restrict__ srcBase,  // &h2[buf][0][0]
    _Float16* __restrict__ dstw,           // &h2[nxt][q&1][16w+l]
    f32x2 xv,
    const half8 (&whh)[4][4], const float (&wih)[4], const float (&bia)[4],
    float& c, int q, int l)
{
    const _Float16* sp = srcBase + (l & 1) * HDIM + 8 * q;
    half8 a0 = *(const half8*)(sp);
    half8 a1 = *(const half8*)(sp + 32);
    half8 a2 = *(const half8*)(sp + 64);
    half8 a3 = *(const half8*)(sp + 96);
    f32x4 A[4], Bv[4];
    #pragma unroll
    for (int g = 0; g < 4; ++g) {
        float c0 = fmaf(xv[0], wih[g], bia[g]);
        float c1 = fmaf(xv[1], wih[g], bia[g]);
        A[g]  = (f32x4){c0, c1, c0, c1};   // rows 4q+r hold elem r&1
        Bv[g] = (f32x4){0.f, 0.f, 0.f, 0.f};
    }
    #pragma unroll
    for (int g = 0; g < 4; ++g) {
        A[g]  = __builtin_amdgcn_mfma_f32_16x16x32_f16(a0, whh[g][0], A[g],  0, 0, 0);
        Bv[g] = __builtin_amdgcn_mfma_f32_16x16x32_f16(a2, whh[g][2], Bv[g], 0, 0, 0);
        A[g]  = __builtin_amdgcn_mfma_f32_16x16x32_f16(a1, whh[g][1], A[g],  0, 0, 0);
        Bv[g] = __builtin_amdgcn_mfma_f32_16x16x32_f16(a3, whh[g][3], Bv[g], 0, 0, 0);
    }
    float v[4];
    #pragma unroll
    for (int g = 0; g < 4; ++g) {
        float e0 = A[g][0] + Bv[g][0];
        float e1 = A[g][1] + Bv[g][1];
        v[g] = (q & 1) ? e1 : e0;          // one v_cndmask
    }
    float ig = fsig_(v[0]), fg = fsig_(v[1]), gg = ftanh_(v[2]), og = fsig_(v[3]);
    c = fmaf(fg, c, ig * gg);
    float hn = og * ftanh_(c);
    if (q < 2) *dstw = (_Float16)hn;
    return hn;
}

__global__ __launch_bounds__(NTHR, 2) void seq2seq_kernel(
    const float* __restrict__ inputs,
    const float* __restrict__ Wih_e, const float* __restrict__ Whh_e, const float* __restrict__ b_e,
    const float* __restrict__ Wih_d, const float* __restrict__ Whh_d, const float* __restrict__ b_d,
    const float* __restrict__ We, const float* __restrict__ Wd,
    const float* __restrict__ Wv, const float* __restrict__ Wf, const float* __restrict__ bfp,
    float* __restrict__ out, int B)
{
    const int tid  = threadIdx.x;
    const int b0   = blockIdx.x * 2;
    const int w    = tid >> 6;
    const int lane = tid & 63;
    const int q    = lane >> 4;
    const int l    = lane & 15;
    const int wrcol = 16 * w + l;
    __shared__ SMem S;

    const _Float16* s0 = &S.h2[0][0][0];
    const _Float16* s1 = &S.h2[1][0][0];
    _Float16* d0 = &S.h2[0][q & 1][wrcol];
    _Float16* d1 = &S.h2[1][q & 1][wrcol];

    // ---- init ----
    if (tid < 2 * HDIM) {
        int e = tid >> 7, j = tid & 127;
        S.h2[0][e][j] = (_Float16)0.0f;
        S.h2[1][e][j] = (_Float16)0.0f;
    }
    if (tid < SEQ * 2) {
        int t = tid >> 1, m = tid & 1;
        S.inp2[t][m] = inputs[(b0 + m) * SEQ + t];
        S.asum[m][t] = 0.0f;
    }
    if (tid < HDIM) { S.wv[tid] = Wv[tid]; S.wf[tid] = Wf[tid]; }
    if (tid < 2) S.ctx2[HDIM][tid] = inputs[(b0 + tid) * SEQ + (SEQ - 1)];

    // ---- encoder weights (B-frags) ----
    half8 whh[4][4];
    float wih[4], bia[4];
    #pragma unroll
    for (int g = 0; g < 4; ++g) {
        int n = g * HDIM + wrcol;
        wih[g] = Wih_e[n];
        bia[g] = b_e[n];
        #pragma unroll
        for (int kt = 0; kt < 4; ++kt) {
            half8 f;
            #pragma unroll
            for (int jj = 0; jj < 8; ++jj)
                f[jj] = (_Float16)Whh_e[(32 * kt + 8 * q + jj) * G4 + n];
            whh[g][kt] = f;
        }
    }
    float c = 0.0f;
    __syncthreads();

    // ---- encoder: 14 steps (7 static-parity pairs) ----
    for (int t = 0; t < SEQ; t += 2) {
        f32x2 x0 = *(const f32x2*)&S.inp2[t][0];
        float hn = lstm_core(s0, d1, x0, whh, wih, bia, c, q, l);
        if (q < 2) S.ench[t][q][wrcol] = (_Float16)hn;
        __syncthreads();
        f32x2 x1 = *(const f32x2*)&S.inp2[t + 1][0];
        hn = lstm_core(s1, d0, x1, whh, wih, bia, c, q, l);
        if (q < 2) S.ench[t + 1][q][wrcol] = (_Float16)hn;
        __syncthreads();
    }
    // h now in h2[0]

    // ---- encWe = enc_out @ We (one-time) ----
    {
        half8 wef[4];
        #pragma unroll
        for (int kt = 0; kt < 4; ++kt) {
            half8 f;
            #pragma unroll
            for (int jj = 0; jj < 8; ++jj)
                f[jj] = (_Float16)We[(32 * kt + 8 * q + jj) * HDIM + wrcol];
            wef[kt] = f;
        }
        for (int t = 0; t < SEQ; ++t) {
            const _Float16* er = &S.ench[t][0][0] + (l & 1) * HDIM + 8 * q;
            f32x4 dv = {0.f, 0.f, 0.f, 0.f};
            #pragma unroll
            for (int kt = 0; kt < 4; ++kt) {
                half8 a = *(const half8*)(er + 32 * kt);
                dv = __builtin_amdgcn_mfma_f32_16x16x32_f16(a, wef[kt], dv, 0, 0, 0);
            }
            float vv = (q & 1) ? dv[1] : dv[0];
            if (q < 2) S.encWe[t][q][wrcol] = (_Float16)vv;
        }
    }

    // ---- decoder weights ----
    half8 wdf[4];
    #pragma unroll
    for (int g = 0; g < 4; ++g) {
        int n = g * HDIM + wrcol;
        wih[g] = Wih_d[n];
        bia[g] = b_d[n];
        #pragma unroll
        for (int kt = 0; kt < 4; ++kt) {
            half8 f;
            #pragma unroll
            for (int jj = 0; jj < 8; ++jj)
                f[jj] = (_Float16)Whh_d[(32 * kt + 8 * q + jj) * G4 + n];
            whh[g][kt] = f;
        }
    }
    #pragma unroll
    for (int kt = 0; kt < 4; ++kt) {
        half8 f;
        #pragma unroll
        for (int jj = 0; jj < 8; ++jj)
            f[jj] = (_Float16)Wd[(32 * kt + 8 * q + jj) * HDIM + wrcol];
        wdf[kt] = f;
    }
    float bf0 = bfp[0];
    __syncthreads();   // encWe + x0 visible

    // ---- decoder: 8 steps, parity alternates (h enters in h2[0]) ----
    #pragma unroll 1
    for (int dd = 0; dd < TLEN; ++dd) {
        const bool even = (dd & 1) == 0;
        const _Float16* sC = even ? s0 : s1;
        const _Float16* sO = even ? s1 : s0;
        _Float16* dC = even ? d0 : d1;
        _Float16* dO = even ? d1 : d0;

        // hWd = h @ Wd
        {
            const _Float16* sp = sC + (l & 1) * HDIM + 8 * q;
            half8 a0 = *(const half8*)(sp);
            half8 a1 = *(const half8*)(sp + 32);
            half8 a2 = *(const half8*)(sp + 64);
            half8 a3 = *(const half8*)(sp + 96);
            f32x4 dv = {0.f, 0.f, 0.f, 0.f};
            dv = __builtin_amdgcn_mfma_f32_16x16x32_f16(a0, wdf[0], dv, 0, 0, 0);
            dv = __builtin_amdgcn_mfma_f32_16x16x32_f16(a1, wdf[1], dv, 0, 0, 0);
            dv = __builtin_amdgcn_mfma_f32_16x16x32_f16(a2, wdf[2], dv, 0, 0, 0);
            dv = __builtin_amdgcn_mfma_f32_16x16x32_f16(a3, wdf[3], dv, 0, 0, 0);
            float vv = (q & 1) ? dv[1] : dv[0];
            if (q < 2) S.hWdh[q][wrcol] = (_Float16)vv;
        }
        __syncthreads();
        // scores
        if (tid < 2 * SEQ * 16) {
            int p = tid >> 4, sub = tid & 15;
            int m = p & 1, t = p >> 1;
            float s = 0.0f;
            #pragma unroll
            for (int i = 0; i < 8; ++i) {
                int j = sub * 8 + i;
                s = fmaf(ftanh_((float)S.encWe[t][m][j] + (float)S.hWdh[m][j]), S.wv[j], s);
            }
            s += __shfl_down(s, 8, 16);
            s += __shfl_down(s, 4, 16);
            s += __shfl_down(s, 2, 16);
            s += __shfl_down(s, 1, 16);
            if (sub == 0) S.score[m][t] = s;
        }
        __syncthreads();
        // softmax over 14 per element
        if (tid < 2) {
            int m = tid;
            float sc[SEQ]; float mx = -1e30f;
            #pragma unroll
            for (int t = 0; t < SEQ; ++t) { sc[t] = S.score[m][t]; mx = fmaxf(mx, sc[t]); }
            float ssum = 0.0f;
            #pragma unroll
            for (int t = 0; t < SEQ; ++t) { float e = __expf(sc[t] - mx); sc[t] = e; ssum += e; }
            float inv = frcp_(ssum);
            #pragma unroll
            for (int t = 0; t < SEQ; ++t) {
                float a = sc[t] * inv;
                S.attnw[m][t] = a;
                S.asum[m][t] += a;
            }
        }
        __syncthreads();
        // context -> ctx2[j][e]
        if (tid < 256) {
            int e = tid >> 7, j = tid & 127;
            float a = 0.0f;
            #pragma unroll
            for (int t = 0; t < SEQ; ++t)
                a = fmaf(S.attnw[e][t], (float)S.ench[t][e][j], a);
            S.ctx2[j][e] = a;
        }
        __syncthreads();

        // decoder LSTM: 129 steps = 64 static-parity pairs + 1
        const f32x2* xp = (const f32x2*)&S.ctx2[0][0];
        #pragma unroll 1
        for (int s2 = 0; s2 < 64; ++s2) {
            (void)lstm_core(sC, dO, xp[2 * s2], whh, wih, bia, c, q, l);
            __syncthreads();
            (void)lstm_core(sO, dC, xp[2 * s2 + 1], whh, wih, bia, c, q, l);
            __syncthreads();
        }
        (void)lstm_core(sC, dO, xp[HDIM], whh, wih, bia, c, q, l);
        __syncthreads();
        // h now in the "other" buffer; output projection -> next x
        const _Float16* hO = even ? &S.h2[1][0][0] : &S.h2[0][0][0];
        if (tid < 32) {
            int m = tid >> 4, part = tid & 15;
            half8 hv = *(const half8*)(hO + m * HDIM + part * 8);
            float s = 0.0f;
            #pragma unroll
            for (int i = 0; i < 8; ++i) s = fmaf((float)hv[i], S.wf[part * 8 + i], s);
            s += __shfl_down(s, 8, 16);
            s += __shfl_down(s, 4, 16);
            s += __shfl_down(s, 2, 16);
            s += __shfl_down(s, 1, 16);
            if (part == 0) {
                float o = s + bf0;
                out[(b0 + m) * TLEN + dd] = o;
                S.ctx2[HDIM][m] = o;
            }
        }
        __syncthreads();
    }

    // total_attn [B, 14, 1]
    if (tid < 2 * SEQ) {
        int m = tid / SEQ, t = tid % SEQ;
        out[B * TLEN + (b0 + m) * SEQ + t] = S.asum[m][t];
    }
}

extern "C" void kernel_launch(void* const* d_in, const int* in_sizes, int n_in,
                              void* d_out, int out_size, void* d_ws, size_t ws_size,
                              hipStream_t stream) {
    const float* inputs = (const float*)d_in[0];
    const float* Wih_e = (const float*)d_in[2];
    const float* Whh_e = (const float*)d_in[3];
    const float* b_e   = (const float*)d_in[4];
    const float* Wih_d = (const float*)d_in[5];
    const float* Whh_d = (const float*)d_in[6];
    const float* b_d   = (const float*)d_in[7];
    const float* We    = (const float*)d_in[8];
    const float* Wd    = (const float*)d_in[9];
    const float* Wv    = (const float*)d_in[10];
    const float* Wf    = (const float*)d_in[11];
    const float* bfp   = (const float*)d_in[12];
    float* out = (float*)d_out;

    const int B = in_sizes[0] / SEQ;  // 512

    seq2seq_kernel<<<dim3(B / 2), dim3(NTHR), 0, stream>>>(
        inputs, Wih_e, Whh_e, b_e, Wih_d, Whh_d, b_d, We, Wd, Wv, Wf, bfp, out, B);
}

// Round 10
// 629.338 us; speedup vs baseline: 1.2684x; 1.0217x over previous
//
#include <hip/hip_runtime.h>

#define HDIM 128
#define SEQ  14
#define G4   512
#define TLEN 8
#define NTHR 512
#define HPITCH 160   // halves per elem row (320 B): elem0 -> banks 0-15, elem1 -> banks 16-31

typedef _Float16 half8 __attribute__((ext_vector_type(8)));
typedef float f32x4 __attribute__((ext_vector_type(4)));
typedef float f32x2 __attribute__((ext_vector_type(2)));

__device__ __forceinline__ float frcp_(float x) { return __builtin_amdgcn_rcpf(x); }
__device__ __forceinline__ float fsig_(float x) { return frcp_(1.0f + __expf(-x)); }
__device__ __forceinline__ float ftanh_(float x) {
    return 1.0f - 2.0f * frcp_(__expf(2.0f * x) + 1.0f);
}

struct __align__(16) SMem {
    _Float16 h2[2][2][HPITCH];             // [buf][elem][col] pitch-320B (bank-colored)
    _Float16 ench[SEQ][2][HDIM];           // encoder outputs
    _Float16 encWe[SEQ][2][HDIM];          // enc_out @ We
    _Float16 hWdh[2][HDIM];                // h @ Wd
    __align__(16) float ctx2[HDIM + 1][2]; // [s][e]; row 128 = x
    __align__(16) float inp2[SEQ][2];
    float attnw[2][SEQ];
    float asum[2][SEQ];
    float score[2][SEQ];
    float wv[HDIM];
    float wf[HDIM];
};

// One LSTM step for 2 batch elements. A-rows alternate elements (row r holds
// elem r&1), so reg0/reg1 of each accumulator are elem0/elem1's gate value in
// every lane. Activation + store predicated to lanes q<2 (the writer lanes).
// Caller must __syncthreads() after.
__device__ __forceinline__ float lstm_core(
    const _Float16* __restrict__ srcBase,  // &h2[buf][0][0]
    _Float16* __restrict__ dstw,           // &h2[nxt][q&1][16w+l]
    f32x2 xv,
    const half8 (&whh)[4][4], const float (&wih)[4], const float (&bia)[4],
    float& c, int q, int l)
{
    const _Float16* sp = srcBase + (l & 1) * HPITCH + 8 * q;
    half8 a0 = *(const half8*)(sp);
    half8 a1 = *(const half8*)(sp + 32);
    half8 a2 = *(const half8*)(sp + 64);
    half8 a3 = *(const half8*)(sp + 96);
    f32x4 A[4];
    #pragma unroll
    for (int g = 0; g < 4; ++g) {
        float c0 = fmaf(xv[0], wih[g], bia[g]);
        float c1 = fmaf(xv[1], wih[g], bia[g]);
        A[g] = (f32x4){c0, c1, c0, c1};
    }
    #pragma unroll
    for (int g = 0; g < 4; ++g) {
        A[g] = __builtin_amdgcn_mfma_f32_16x16x32_f16(a0, whh[g][0], A[g], 0, 0, 0);
        A[g] = __builtin_amdgcn_mfma_f32_16x16x32_f16(a1, whh[g][1], A[g], 0, 0, 0);
        A[g] = __builtin_amdgcn_mfma_f32_16x16x32_f16(a2, whh[g][2], A[g], 0, 0, 0);
        A[g] = __builtin_amdgcn_mfma_f32_16x16x32_f16(a3, whh[g][3], A[g], 0, 0, 0);
    }
    float hn = 0.0f;
    if (q < 2) {                           // writer lanes only (lanes 0-31)
        float v0 = q ? A[0][1] : A[0][0];
        float v1 = q ? A[1][1] : A[1][0];
        float v2 = q ? A[2][1] : A[2][0];
        float v3 = q ? A[3][1] : A[3][0];
        float ig = fsig_(v0), fg = fsig_(v1), gg = ftanh_(v2), og = fsig_(v3);
        c = fmaf(fg, c, ig * gg);
        hn = og * ftanh_(c);
        *dstw = (_Float16)hn;
    }
    return hn;
}

__global__ __launch_bounds__(NTHR, 2) void seq2seq_kernel(
    const float* __restrict__ inputs,
    const float* __restrict__ Wih_e, const float* __restrict__ Whh_e, const float* __restrict__ b_e,
    const float* __restrict__ Wih_d, const float* __restrict__ Whh_d, const float* __restrict__ b_d,
    const float* __restrict__ We, const float* __restrict__ Wd,
    const float* __restrict__ Wv, const float* __restrict__ Wf, const float* __restrict__ bfp,
    float* __restrict__ out, int B)
{
    const int tid  = threadIdx.x;
    const int b0   = blockIdx.x * 2;
    const int w    = tid >> 6;
    const int lane = tid & 63;
    const int q    = lane >> 4;
    const int l    = lane & 15;
    const int wrcol = 16 * w + l;
    __shared__ SMem S;

    const _Float16* s0 = &S.h2[0][0][0];
    const _Float16* s1 = &S.h2[1][0][0];
    _Float16* d0 = &S.h2[0][q & 1][wrcol];
    _Float16* d1 = &S.h2[1][q & 1][wrcol];

    // ---- init ----
    if (tid < 2 * HDIM) {
        int e = tid >> 7, j = tid & 127;
        S.h2[0][e][j] = (_Float16)0.0f;
        S.h2[1][e][j] = (_Float16)0.0f;
    }
    if (tid < SEQ * 2) {
        int t = tid >> 1, m = tid & 1;
        S.inp2[t][m] = inputs[(b0 + m) * SEQ + t];
        S.asum[m][t] = 0.0f;
    }
    if (tid < HDIM) { S.wv[tid] = Wv[tid]; S.wf[tid] = Wf[tid]; }
    if (tid < 2) S.ctx2[HDIM][tid] = inputs[(b0 + tid) * SEQ + (SEQ - 1)];

    // ---- encoder weights (B-frags) ----
    half8 whh[4][4];
    float wih[4], bia[4];
    #pragma unroll
    for (int g = 0; g < 4; ++g) {
        int n = g * HDIM + wrcol;
        wih[g] = Wih_e[n];
        bia[g] = b_e[n];
        #pragma unroll
        for (int kt = 0; kt < 4; ++kt) {
            half8 f;
            #pragma unroll
            for (int jj = 0; jj < 8; ++jj)
                f[jj] = (_Float16)Whh_e[(32 * kt + 8 * q + jj) * G4 + n];
            whh[g][kt] = f;
        }
    }
    float c = 0.0f;
    __syncthreads();

    // ---- encoder: 14 steps (7 static-parity pairs) ----
    for (int t = 0; t < SEQ; t += 2) {
        f32x2 x0 = *(const f32x2*)&S.inp2[t][0];
        float hn = lstm_core(s0, d1, x0, whh, wih, bia, c, q, l);
        if (q < 2) S.ench[t][q][wrcol] = (_Float16)hn;
        __syncthreads();
        f32x2 x1 = *(const f32x2*)&S.inp2[t + 1][0];
        hn = lstm_core(s1, d0, x1, whh, wih, bia, c, q, l);
        if (q < 2) S.ench[t + 1][q][wrcol] = (_Float16)hn;
        __syncthreads();
    }
    // h now in h2[0]

    // ---- encWe = enc_out @ We (one-time) ----
    {
        half8 wef[4];
        #pragma unroll
        for (int kt = 0; kt < 4; ++kt) {
            half8 f;
            #pragma unroll
            for (int jj = 0; jj < 8; ++jj)
                f[jj] = (_Float16)We[(32 * kt + 8 * q + jj) * HDIM + wrcol];
            wef[kt] = f;
        }
        for (int t = 0; t < SEQ; ++t) {
            const _Float16* er = &S.ench[t][0][0] + (l & 1) * HDIM + 8 * q;
            f32x4 dv = {0.f, 0.f, 0.f, 0.f};
            #pragma unroll
            for (int kt = 0; kt < 4; ++kt) {
                half8 a = *(const half8*)(er + 32 * kt);
                dv = __builtin_amdgcn_mfma_f32_16x16x32_f16(a, wef[kt], dv, 0, 0, 0);
            }
            if (q < 2) S.encWe[t][q][wrcol] = (_Float16)(q ? dv[1] : dv[0]);
        }
    }

    // ---- decoder weights ----
    half8 wdf[4];
    #pragma unroll
    for (int g = 0; g < 4; ++g) {
        int n = g * HDIM + wrcol;
        wih[g] = Wih_d[n];
        bia[g] = b_d[n];
        #pragma unroll
        for (int kt = 0; kt < 4; ++kt) {
            half8 f;
            #pragma unroll
            for (int jj = 0; jj < 8; ++jj)
                f[jj] = (_Float16)Whh_d[(32 * kt + 8 * q + jj) * G4 + n];
            whh[g][kt] = f;
        }
    }
    #pragma unroll
    for (int kt = 0; kt < 4; ++kt) {
        half8 f;
        #pragma unroll
        for (int jj = 0; jj < 8; ++jj)
            f[jj] = (_Float16)Wd[(32 * kt + 8 * q + jj) * HDIM + wrcol];
        wdf[kt] = f;
    }
    float bf0 = bfp[0];
    __syncthreads();   // encWe + x0 visible

    // ---- decoder: 8 steps, parity alternates (h enters in h2[0]) ----
    #pragma unroll 1
    for (int dd = 0; dd < TLEN; ++dd) {
        const bool even = (dd & 1) == 0;
        const _Float16* sC = even ? s0 : s1;
        const _Float16* sO = even ? s1 : s0;
        _Float16* dC = even ? d0 : d1;
        _Float16* dO = even ? d1 : d0;

        // hWd = h @ Wd
        {
            const _Float16* sp = sC + (l & 1) * HPITCH + 8 * q;
            half8 a0 = *(const half8*)(sp);
            half8 a1 = *(const half8*)(sp + 32);
            half8 a2 = *(const half8*)(sp + 64);
            half8 a3 = *(const half8*)(sp + 96);
            f32x4 dv = {0.f, 0.f, 0.f, 0.f};
            dv = __builtin_amdgcn_mfma_f32_16x16x32_f16(a0, wdf[0], dv, 0, 0, 0);
            dv = __builtin_amdgcn_mfma_f32_16x16x32_f16(a1, wdf[1], dv, 0, 0, 0);
            dv = __builtin_amdgcn_mfma_f32_16x16x32_f16(a2, wdf[2], dv, 0, 0, 0);
            dv = __builtin_amdgcn_mfma_f32_16x16x32_f16(a3, wdf[3], dv, 0, 0, 0);
            if (q < 2) S.hWdh[q][wrcol] = (_Float16)(q ? dv[1] : dv[0]);
        }
        __syncthreads();
        // scores
        if (tid < 2 * SEQ * 16) {
            int p = tid >> 4, sub = tid & 15;
            int m = p & 1, t = p >> 1;
            float s = 0.0f;
            #pragma unroll
            for (int i = 0; i < 8; ++i) {
                int j = sub * 8 + i;
                s = fmaf(ftanh_((float)S.encWe[t][m][j] + (float)S.hWdh[m][j]), S.wv[j], s);
            }
            s += __shfl_down(s, 8, 16);
            s += __shfl_down(s, 4, 16);
            s += __shfl_down(s, 2, 16);
            s += __shfl_down(s, 1, 16);
            if (sub == 0) S.score[m][t] = s;
        }
        __syncthreads();
        // softmax over 14 per element
        if (tid < 2) {
            int m = tid;
            float sc[SEQ]; float mx = -1e30f;
            #pragma unroll
            for (int t = 0; t < SEQ; ++t) { sc[t] = S.score[m][t]; mx = fmaxf(mx, sc[t]); }
            float ssum = 0.0f;
            #pragma unroll
            for (int t = 0; t < SEQ; ++t) { float e = __expf(sc[t] - mx); sc[t] = e; ssum += e; }
            float inv = frcp_(ssum);
            #pragma unroll
            for (int t = 0; t < SEQ; ++t) {
                float a = sc[t] * inv;
                S.attnw[m][t] = a;
                S.asum[m][t] += a;
            }
        }
        __syncthreads();
        // context -> ctx2[j][e]
        if (tid < 256) {
            int e = tid >> 7, j = tid & 127;
            float a = 0.0f;
            #pragma unroll
            for (int t = 0; t < SEQ; ++t)
                a = fmaf(S.attnw[e][t], (float)S.ench[t][e][j], a);
            S.ctx2[j][e] = a;
        }
        __syncthreads();

        // decoder LSTM: 129 steps = 64 static-parity pairs + 1
        const f32x2* xp = (const f32x2*)&S.ctx2[0][0];
        #pragma unroll 1
        for (int s2 = 0; s2 < 64; ++s2) {
            (void)lstm_core(sC, dO, xp[2 * s2], whh, wih, bia, c, q, l);
            __syncthreads();
            (void)lstm_core(sO, dC, xp[2 * s2 + 1], whh, wih, bia, c, q, l);
            __syncthreads();
        }
        (void)lstm_core(sC, dO, xp[HDIM], whh, wih, bia, c, q, l);
        __syncthreads();
        // h now in the "other" buffer; output projection -> next x
        const _Float16* hO = even ? &S.h2[1][0][0] : &S.h2[0][0][0];
        if (tid < 32) {
            int m = tid >> 4, part = tid & 15;
            half8 hv = *(const half8*)(hO + m * HPITCH + part * 8);
            float s = 0.0f;
            #pragma unroll
            for (int i = 0; i < 8; ++i) s = fmaf((float)hv[i], S.wf[part * 8 + i], s);
            s += __shfl_down(s, 8, 16);
            s += __shfl_down(s, 4, 16);
            s += __shfl_down(s, 2, 16);
            s += __shfl_down(s, 1, 16);
            if (part == 0) {
                float o = s + bf0;
                out[(b0 + m) * TLEN + dd] = o;
                S.ctx2[HDIM][m] = o;
            }
        }
        __syncthreads();
    }

    // total_attn [B, 14, 1]
    if (tid < 2 * SEQ) {
        int m = tid / SEQ, t = tid % SEQ;
        out[B * TLEN + (b0 + m) * SEQ + t] = S.asum[m][t];
    }
}

extern "C" void kernel_launch(void* const* d_in, const int* in_sizes, int n_in,
                              void* d_out, int out_size, void* d_ws, size_t ws_size,
                              hipStream_t stream) {
    const float* inputs = (const float*)d_in[0];
    const float* Wih_e = (const float*)d_in[2];
    const float* Whh_e = (const float*)d_in[3];
    const float* b_e   = (const float*)d_in[4];
    const float* Wih_d = (const float*)d_in[5];
    const float* Whh_d = (const float*)d_in[6];
    const float* b_d   = (const float*)d_in[7];
    const float* We    = (const float*)d_in[8];
    const float* Wd    = (const float*)d_in[9];
    const float* Wv    = (const float*)d_in[10];
    const float* Wf    = (const float*)d_in[11];
    const float* bfp   = (const float*)d_in[12];
    float* out = (float*)d_out;

    const int B = in_sizes[0] / SEQ;  // 512

    seq2seq_kernel<<<dim3(B / 2), dim3(NTHR), 0, stream>>>(
        inputs, Wih_e, Whh_e, b_e, Wih_d, Whh_d, b_d, We, Wd, Wv, Wf, bfp, out, B);
}

// Round 11
// 563.013 us; speedup vs baseline: 1.4178x; 1.1178x over previous
//
#include <hip/hip_runtime.h>

#define HDIM 128
#define SEQ  14
#define G4   512
#define TLEN 8
#define NTHR 512
#define HPITCH 160   // halves per elem row (320 B): elem0 banks 0-15, elem1 banks 16-31

typedef _Float16 half8 __attribute__((ext_vector_type(8)));
typedef float f32x4 __attribute__((ext_vector_type(4)));
typedef float f32x2 __attribute__((ext_vector_type(2)));

#define LOG2E  1.44269504f
#define LOG2E2 2.88539008f

__device__ __forceinline__ float frcp_(float x) { return __builtin_amdgcn_rcpf(x); }
#if defined(__has_builtin)
#if __has_builtin(__builtin_amdgcn_exp2f)
#define EXP2_(x) __builtin_amdgcn_exp2f(x)
#endif
#endif
#ifndef EXP2_
#define EXP2_(x) __expf((x) * 0.69314718f)
#endif
// inputs pre-scaled by log2e (sig) / 2*log2e (tanh):
__device__ __forceinline__ float fsigP_(float y)  { return frcp_(1.0f + EXP2_(-y)); }
__device__ __forceinline__ float ftanhP_(float y) { return 1.0f - 2.0f * frcp_(EXP2_(y) + 1.0f); }
// unscaled (scores path):
__device__ __forceinline__ float ftanh_(float x)  { return ftanhP_(x * LOG2E2); }

struct __align__(16) SMem {
    _Float16 h2[2][2][HPITCH];             // [buf][elem][col], bank-colored
    _Float16 ench[SEQ][2][HPITCH];         // encoder outputs, bank-colored
    _Float16 encWe[SEQ][2][HDIM];          // enc_out @ We
    _Float16 hWdh[2][HDIM];                // h @ Wd
    __align__(16) float ctx2[HDIM + 1][2]; // [s][e]; row 128 = x
    __align__(16) float inp2[SEQ][2];
    float attnw[2][SEQ];
    float asum[2][SEQ];
    float score[2][SEQ];
    float wv[HDIM];
    float wf[HDIM];
};

// One LSTM step for 2 batch elements. A-row r carries elem (r>>2)&1, so for
// writer lanes q<2, D reg0 (= row 4q) is the lane's own element's gate value:
// no cross-lane motion, no post-MFMA selects. Weights pre-scaled by log2e
// (gates i,f,o) / 2*log2e (gate g) so activation uses bare v_exp_f32.
// Caller must __syncthreads() after.
__device__ __forceinline__ float lstm_core(
    const _Float16* __restrict__ srcBase,  // &h2[buf][0][0]
    _Float16* __restrict__ dstw,           // &h2[nxt][q][16w+l] (q<2)
    f32x2 xv,
    const half8 (&whh)[4][4], const float (&wih)[4], const float (&bia)[4],
    float& c, int q, int l)
{
    const _Float16* sp = srcBase + ((l >> 2) & 1) * HPITCH + 8 * q;
    half8 a0 = *(const half8*)(sp);
    half8 a1 = *(const half8*)(sp + 32);
    half8 a2 = *(const half8*)(sp + 64);
    half8 a3 = *(const half8*)(sp + 96);
    const bool odd = (q & 1);
    f32x4 A[4];
    #pragma unroll
    for (int g = 0; g < 4; ++g) {
        float ce = fmaf(odd ? xv[1] : xv[0], wih[g], bia[g]);  // lane's row-elem
        A[g] = (f32x4){ce, ce, ce, ce};
    }
    #pragma unroll
    for (int g = 0; g < 4; ++g) {
        A[g] = __builtin_amdgcn_mfma_f32_16x16x32_f16(a0, whh[g][0], A[g], 0, 0, 0);
        A[g] = __builtin_amdgcn_mfma_f32_16x16x32_f16(a1, whh[g][1], A[g], 0, 0, 0);
        A[g] = __builtin_amdgcn_mfma_f32_16x16x32_f16(a2, whh[g][2], A[g], 0, 0, 0);
        A[g] = __builtin_amdgcn_mfma_f32_16x16x32_f16(a3, whh[g][3], A[g], 0, 0, 0);
    }
    float hn = 0.0f;
    if (q < 2) {                           // writer lanes; reg0 = own element
        float ig = fsigP_(A[0][0]);
        float fg = fsigP_(A[1][0]);
        float gg = ftanhP_(A[2][0]);
        float og = fsigP_(A[3][0]);
        c = fmaf(fg, c, ig * gg);
        hn = og * ftanhP_(c * LOG2E2);
        *dstw = (_Float16)hn;
    }
    return hn;
}

__global__ __launch_bounds__(NTHR, 2) void seq2seq_kernel(
    const float* __restrict__ inputs,
    const float* __restrict__ Wih_e, const float* __restrict__ Whh_e, const float* __restrict__ b_e,
    const float* __restrict__ Wih_d, const float* __restrict__ Whh_d, const float* __restrict__ b_d,
    const float* __restrict__ We, const float* __restrict__ Wd,
    const float* __restrict__ Wv, const float* __restrict__ Wf, const float* __restrict__ bfp,
    float* __restrict__ out, int B)
{
    const int tid  = threadIdx.x;
    const int b0   = blockIdx.x * 2;
    const int w    = tid >> 6;
    const int lane = tid & 63;
    const int q    = lane >> 4;
    const int l    = lane & 15;
    const int wrcol = 16 * w + l;
    __shared__ SMem S;

    const _Float16* s0 = &S.h2[0][0][0];
    const _Float16* s1 = &S.h2[1][0][0];
    _Float16* d0 = &S.h2[0][q & 1][wrcol];
    _Float16* d1 = &S.h2[1][q & 1][wrcol];

    // gate scales: i,f,o -> log2e ; g -> 2*log2e
    const float gscale[4] = {LOG2E, LOG2E, LOG2E2, LOG2E};

    // ---- init ----
    if (tid < 2 * HDIM) {
        int e = tid >> 7, j = tid & 127;
        S.h2[0][e][j] = (_Float16)0.0f;
        S.h2[1][e][j] = (_Float16)0.0f;
    }
    if (tid < SEQ * 2) {
        int t = tid >> 1, m = tid & 1;
        S.inp2[t][m] = inputs[(b0 + m) * SEQ + t];
        S.asum[m][t] = 0.0f;
    }
    if (tid < HDIM) { S.wv[tid] = Wv[tid]; S.wf[tid] = Wf[tid]; }
    if (tid < 2) S.ctx2[HDIM][tid] = inputs[(b0 + tid) * SEQ + (SEQ - 1)];

    // ---- encoder weights (B-frags, pre-scaled) ----
    half8 whh[4][4];
    float wih[4], bia[4];
    #pragma unroll
    for (int g = 0; g < 4; ++g) {
        int n = g * HDIM + wrcol;
        float sc = gscale[g];
        wih[g] = Wih_e[n] * sc;
        bia[g] = b_e[n] * sc;
        #pragma unroll
        for (int kt = 0; kt < 4; ++kt) {
            half8 f;
            #pragma unroll
            for (int jj = 0; jj < 8; ++jj)
                f[jj] = (_Float16)(Whh_e[(32 * kt + 8 * q + jj) * G4 + n] * sc);
            whh[g][kt] = f;
        }
    }
    float c = 0.0f;
    __syncthreads();

    // ---- encoder: 14 steps (7 static-parity pairs) ----
    for (int t = 0; t < SEQ; t += 2) {
        f32x2 x0 = *(const f32x2*)&S.inp2[t][0];
        float hn = lstm_core(s0, d1, x0, whh, wih, bia, c, q, l);
        if (q < 2) S.ench[t][q][wrcol] = (_Float16)hn;
        __syncthreads();
        f32x2 x1 = *(const f32x2*)&S.inp2[t + 1][0];
        hn = lstm_core(s1, d0, x1, whh, wih, bia, c, q, l);
        if (q < 2) S.ench[t + 1][q][wrcol] = (_Float16)hn;
        __syncthreads();
    }
    // h now in h2[0]

    // ---- encWe = enc_out @ We (one-time; unscaled weights) ----
    {
        half8 wef[4];
        #pragma unroll
        for (int kt = 0; kt < 4; ++kt) {
            half8 f;
            #pragma unroll
            for (int jj = 0; jj < 8; ++jj)
                f[jj] = (_Float16)We[(32 * kt + 8 * q + jj) * HDIM + wrcol];
            wef[kt] = f;
        }
        for (int t = 0; t < SEQ; ++t) {
            const _Float16* er = &S.ench[t][0][0] + ((l >> 2) & 1) * HPITCH + 8 * q;
            f32x4 dv = {0.f, 0.f, 0.f, 0.f};
            #pragma unroll
            for (int kt = 0; kt < 4; ++kt) {
                half8 a = *(const half8*)(er + 32 * kt);
                dv = __builtin_amdgcn_mfma_f32_16x16x32_f16(a, wef[kt], dv, 0, 0, 0);
            }
            if (q < 2) S.encWe[t][q][wrcol] = (_Float16)dv[0];  // reg0 = row 4q = elem q
        }
    }

    // ---- decoder weights (pre-scaled) ----
    half8 wdf[4];
    #pragma unroll
    for (int g = 0; g < 4; ++g) {
        int n = g * HDIM + wrcol;
        float sc = gscale[g];
        wih[g] = Wih_d[n] * sc;
        bia[g] = b_d[n] * sc;
        #pragma unroll
        for (int kt = 0; kt < 4; ++kt) {
            half8 f;
            #pragma unroll
            for (int jj = 0; jj < 8; ++jj)
                f[jj] = (_Float16)(Whh_d[(32 * kt + 8 * q + jj) * G4 + n] * sc);
            whh[g][kt] = f;
        }
    }
    #pragma unroll
    for (int kt = 0; kt < 4; ++kt) {
        half8 f;
        #pragma unroll
        for (int jj = 0; jj < 8; ++jj)
            f[jj] = (_Float16)Wd[(32 * kt + 8 * q + jj) * HDIM + wrcol];
        wdf[kt] = f;
    }
    float bf0 = bfp[0];
    __syncthreads();   // encWe + x0 visible

    // ---- decoder: 8 steps, parity alternates (h enters in h2[0]) ----
    #pragma unroll 1
    for (int dd = 0; dd < TLEN; ++dd) {
        const bool even = (dd & 1) == 0;
        const _Float16* sC = even ? s0 : s1;
        const _Float16* sO = even ? s1 : s0;
        _Float16* dC = even ? d0 : d1;
        _Float16* dO = even ? d1 : d0;

        // hWd = h @ Wd
        {
            const _Float16* sp = sC + ((l >> 2) & 1) * HPITCH + 8 * q;
            half8 a0 = *(const half8*)(sp);
            half8 a1 = *(const half8*)(sp + 32);
            half8 a2 = *(const half8*)(sp + 64);
            half8 a3 = *(const half8*)(sp + 96);
            f32x4 dv = {0.f, 0.f, 0.f, 0.f};
            dv = __builtin_amdgcn_mfma_f32_16x16x32_f16(a0, wdf[0], dv, 0, 0, 0);
            dv = __builtin_amdgcn_mfma_f32_16x16x32_f16(a1, wdf[1], dv, 0, 0, 0);
            dv = __builtin_amdgcn_mfma_f32_16x16x32_f16(a2, wdf[2], dv, 0, 0, 0);
            dv = __builtin_amdgcn_mfma_f32_16x16x32_f16(a3, wdf[3], dv, 0, 0, 0);
            if (q < 2) S.hWdh[q][wrcol] = (_Float16)dv[0];
        }
        __syncthreads();
        // scores
        if (tid < 2 * SEQ * 16) {
            int p = tid >> 4, sub = tid & 15;
            int m = p & 1, t = p >> 1;
            float s = 0.0f;
            #pragma unroll
            for (int i = 0; i < 8; ++i) {
                int j = sub * 8 + i;
                s = fmaf(ftanh_((float)S.encWe[t][m][j] + (float)S.hWdh[m][j]), S.wv[j], s);
            }
            s += __shfl_down(s, 8, 16);
            s += __shfl_down(s, 4, 16);
            s += __shfl_down(s, 2, 16);
            s += __shfl_down(s, 1, 16);
            if (sub == 0) S.score[m][t] = s;
        }
        __syncthreads();
        // softmax over 14 per element
        if (tid < 2) {
            int m = tid;
            float sc[SEQ]; float mx = -1e30f;
            #pragma unroll
            for (int t = 0; t < SEQ; ++t) { sc[t] = S.score[m][t]; mx = fmaxf(mx, sc[t]); }
            float ssum = 0.0f;
            #pragma unroll
            for (int t = 0; t < SEQ; ++t) { float e = __expf(sc[t] - mx); sc[t] = e; ssum += e; }
            float inv = frcp_(ssum);
            #pragma unroll
            for (int t = 0; t < SEQ; ++t) {
                float a = sc[t] * inv;
                S.attnw[m][t] = a;
                S.asum[m][t] += a;
            }
        }
        __syncthreads();
        // context -> ctx2[j][e]
        if (tid < 256) {
            int e = tid >> 7, j = tid & 127;
            float a = 0.0f;
            #pragma unroll
            for (int t = 0; t < SEQ; ++t)
                a = fmaf(S.attnw[e][t], (float)S.ench[t][e][j], a);
            S.ctx2[j][e] = a;
        }
        __syncthreads();

        // decoder LSTM: 129 steps = 64 static-parity pairs + 1
        const f32x2* xp = (const f32x2*)&S.ctx2[0][0];
        #pragma unroll 1
        for (int s2 = 0; s2 < 64; ++s2) {
            (void)lstm_core(sC, dO, xp[2 * s2], whh, wih, bia, c, q, l);
            __syncthreads();
            (void)lstm_core(sO, dC, xp[2 * s2 + 1], whh, wih, bia, c, q, l);
            __syncthreads();
        }
        (void)lstm_core(sC, dO, xp[HDIM], whh, wih, bia, c, q, l);
        __syncthreads();
        // h now in the "other" buffer; output projection -> next x
        const _Float16* hO = even ? &S.h2[1][0][0] : &S.h2[0][0][0];
        if (tid < 32) {
            int m = tid >> 4, part = tid & 15;
            half8 hv = *(const half8*)(hO + m * HPITCH + part * 8);
            float s = 0.0f;
            #pragma unroll
            for (int i = 0; i < 8; ++i) s = fmaf((float)hv[i], S.wf[part * 8 + i], s);
            s += __shfl_down(s, 8, 16);
            s += __shfl_down(s, 4, 16);
            s += __shfl_down(s, 2, 16);
            s += __shfl_down(s, 1, 16);
            if (part == 0) {
                float o = s + bf0;
                out[(b0 + m) * TLEN + dd] = o;
                S.ctx2[HDIM][m] = o;
            }
        }
        __syncthreads();
    }

    // total_attn [B, 14, 1]
    if (tid < 2 * SEQ) {
        int m = tid / SEQ, t = tid % SEQ;
        out[B * TLEN + (b0 + m) * SEQ + t] = S.asum[m][t];
    }
}

extern "C" void kernel_launch(void* const* d_in, const int* in_sizes, int n_in,
                              void* d_out, int out_size, void* d_ws, size_t ws_size,
                              hipStream_t stream) {
    const float* inputs = (const float*)d_in[0];
    const float* Wih_e = (const float*)d_in[2];
    const float* Whh_e = (const float*)d_in[3];
    const float* b_e   = (const float*)d_in[4];
    const float* Wih_d = (const float*)d_in[5];
    const float* Whh_d = (const float*)d_in[6];
    const float* b_d   = (const float*)d_in[7];
    const float* We    = (const float*)d_in[8];
    const float* Wd    = (const float*)d_in[9];
    const float* Wv    = (const float*)d_in[10];
    const float* Wf    = (const float*)d_in[11];
    const float* bfp   = (const float*)d_in[12];
    float* out = (float*)d_out;

    const int B = in_sizes[0] / SEQ;  // 512

    seq2seq_kernel<<<dim3(B / 2), dim3(NTHR), 0, stream>>>(
        inputs, Wih_e, Whh_e, b_e, Wih_d, Whh_d, b_d, We, Wd, Wv, Wf, bfp, out, B);
}

// Round 12
// 508.277 us; speedup vs baseline: 1.5705x; 1.1077x over previous
//
#include <hip/hip_runtime.h>

#define HDIM 128
#define SEQ  14
#define G4   512
#define TLEN 8
#define NTHR 512
#define HPITCH 160   // halves per elem row (320 B): elem0 banks 0-15, elem1 banks 16-31

typedef _Float16 half8 __attribute__((ext_vector_type(8)));
typedef float f32x4 __attribute__((ext_vector_type(4)));
typedef float f32x2 __attribute__((ext_vector_type(2)));

#define LOG2E  1.44269504f
#define LOG2E2 2.88539008f

__device__ __forceinline__ float frcp_(float x) { return __builtin_amdgcn_rcpf(x); }
#if defined(__has_builtin)
#if __has_builtin(__builtin_amdgcn_exp2f)
#define EXP2_(x) __builtin_amdgcn_exp2f(x)
#endif
#endif
#ifndef EXP2_
#define EXP2_(x) __expf((x) * 0.69314718f)
#endif
// inputs pre-scaled by log2e (sig) / 2*log2e (tanh):
__device__ __forceinline__ float fsigP_(float y)  { return frcp_(1.0f + EXP2_(-y)); }
__device__ __forceinline__ float ftanhP_(float y) { return 1.0f - 2.0f * frcp_(EXP2_(y) + 1.0f); }
// unscaled (scores path):
__device__ __forceinline__ float ftanh_(float x)  { return ftanhP_(x * LOG2E2); }

struct __align__(16) SMem {
    __align__(16) float zq[4];             // persistent zero quad (opaque to compiler)
    _Float16 h2[2][2][HPITCH];             // [buf][elem][col], bank-colored
    _Float16 ench[SEQ][2][HPITCH];         // encoder outputs, bank-colored
    _Float16 encWe[SEQ][2][HDIM];          // enc_out @ We
    _Float16 hWdh[2][HDIM];                // h @ Wd
    __align__(16) float ctx2[HDIM + 1][2]; // [s][e]; row 128 = x
    __align__(16) float inp2[SEQ][2];
    float attnw[2][SEQ];
    float asum[2][SEQ];
    float score[2][SEQ];
    float wv[HDIM];
    float wf[HDIM];
};

// One LSTM step for 2 batch elements. A-row r carries elem (r>>2)&1, so for
// writer lanes q<2, D reg0 (= row 4q) is the lane's own element's gate value.
// MFMA chains start from a persistent zero quad (no per-step acc splat); the
// x*wih+b term is added post-MFMA to the single live scalar under the q<2
// mask. Weights pre-scaled by log2e (i,f,o) / 2*log2e (g) for bare v_exp_f32.
// Caller must __syncthreads() after (and may issue prefetches before it).
__device__ __forceinline__ float lstm_core(
    const _Float16* __restrict__ srcBase,  // &h2[buf][0][0]
    _Float16* __restrict__ dstw,           // &h2[nxt][q][16w+l] (q<2)
    f32x2 xv, f32x4 zeroq,
    const half8 (&whh)[4][4], const float (&wih)[4], const float (&bia)[4],
    float& c, int q, int l)
{
    const _Float16* sp = srcBase + ((l >> 2) & 1) * HPITCH + 8 * q;
    half8 a0 = *(const half8*)(sp);
    half8 a1 = *(const half8*)(sp + 32);
    half8 a2 = *(const half8*)(sp + 64);
    half8 a3 = *(const half8*)(sp + 96);
    f32x4 A[4];
    #pragma unroll
    for (int g = 0; g < 4; ++g) {
        A[g] = __builtin_amdgcn_mfma_f32_16x16x32_f16(a0, whh[g][0], zeroq, 0, 0, 0);
        A[g] = __builtin_amdgcn_mfma_f32_16x16x32_f16(a1, whh[g][1], A[g], 0, 0, 0);
        A[g] = __builtin_amdgcn_mfma_f32_16x16x32_f16(a2, whh[g][2], A[g], 0, 0, 0);
        A[g] = __builtin_amdgcn_mfma_f32_16x16x32_f16(a3, whh[g][3], A[g], 0, 0, 0);
    }
    float hn = 0.0f;
    if (q < 2) {                           // writer lanes; reg0 = own element
        float x = (q & 1) ? xv[1] : xv[0];
        float ig = fsigP_(fmaf(x, wih[0], bia[0]) + A[0][0]);
        float fg = fsigP_(fmaf(x, wih[1], bia[1]) + A[1][0]);
        float gg = ftanhP_(fmaf(x, wih[2], bia[2]) + A[2][0]);
        float og = fsigP_(fmaf(x, wih[3], bia[3]) + A[3][0]);
        c = fmaf(fg, c, ig * gg);
        hn = og * ftanhP_(c * LOG2E2);
        *dstw = (_Float16)hn;
    }
    return hn;
}

__global__ __launch_bounds__(NTHR, 2) void seq2seq_kernel(
    const float* __restrict__ inputs,
    const float* __restrict__ Wih_e, const float* __restrict__ Whh_e, const float* __restrict__ b_e,
    const float* __restrict__ Wih_d, const float* __restrict__ Whh_d, const float* __restrict__ b_d,
    const float* __restrict__ We, const float* __restrict__ Wd,
    const float* __restrict__ Wv, const float* __restrict__ Wf, const float* __restrict__ bfp,
    float* __restrict__ out, int B)
{
    const int tid  = threadIdx.x;
    const int b0   = blockIdx.x * 2;
    const int w    = tid >> 6;
    const int lane = tid & 63;
    const int q    = lane >> 4;
    const int l    = lane & 15;
    const int wrcol = 16 * w + l;
    __shared__ SMem S;

    const _Float16* s0 = &S.h2[0][0][0];
    const _Float16* s1 = &S.h2[1][0][0];
    _Float16* d0 = &S.h2[0][q & 1][wrcol];
    _Float16* d1 = &S.h2[1][q & 1][wrcol];

    // gate scales: i,f,o -> log2e ; g -> 2*log2e
    const float gscale[4] = {LOG2E, LOG2E, LOG2E2, LOG2E};

    // ---- init ----
    if (tid < 4) S.zq[tid] = 0.0f;
    if (tid < 2 * HDIM) {
        int e = tid >> 7, j = tid & 127;
        S.h2[0][e][j] = (_Float16)0.0f;
        S.h2[1][e][j] = (_Float16)0.0f;
    }
    if (tid < SEQ * 2) {
        int t = tid >> 1, m = tid & 1;
        S.inp2[t][m] = inputs[(b0 + m) * SEQ + t];
        S.asum[m][t] = 0.0f;
    }
    if (tid < HDIM) { S.wv[tid] = Wv[tid]; S.wf[tid] = Wf[tid]; }
    if (tid < 2) S.ctx2[HDIM][tid] = inputs[(b0 + tid) * SEQ + (SEQ - 1)];

    // ---- encoder weights (B-frags, pre-scaled) ----
    half8 whh[4][4];
    float wih[4], bia[4];
    #pragma unroll
    for (int g = 0; g < 4; ++g) {
        int n = g * HDIM + wrcol;
        float sc = gscale[g];
        wih[g] = Wih_e[n] * sc;
        bia[g] = b_e[n] * sc;
        #pragma unroll
        for (int kt = 0; kt < 4; ++kt) {
            half8 f;
            #pragma unroll
            for (int jj = 0; jj < 8; ++jj)
                f[jj] = (_Float16)(Whh_e[(32 * kt + 8 * q + jj) * G4 + n] * sc);
            whh[g][kt] = f;
        }
    }
    float c = 0.0f;
    __syncthreads();

    const f32x4 zeroq = *(const f32x4*)S.zq;   // opaque zeros: 4 persistent VGPRs

    // ---- encoder: 14 steps (7 static-parity pairs), x prefetched across barrier ----
    f32x2 xv = *(const f32x2*)&S.inp2[0][0];
    for (int t = 0; t < SEQ; t += 2) {
        float hn = lstm_core(s0, d1, xv, zeroq, whh, wih, bia, c, q, l);
        if (q < 2) S.ench[t][q][wrcol] = (_Float16)hn;
        xv = *(const f32x2*)&S.inp2[t + 1][0];
        __syncthreads();
        hn = lstm_core(s1, d0, xv, zeroq, whh, wih, bia, c, q, l);
        if (q < 2) S.ench[t + 1][q][wrcol] = (_Float16)hn;
        if (t + 2 < SEQ) xv = *(const f32x2*)&S.inp2[t + 2][0];
        __syncthreads();
    }
    // h now in h2[0]

    // ---- encWe = enc_out @ We (one-time; unscaled weights) ----
    {
        half8 wef[4];
        #pragma unroll
        for (int kt = 0; kt < 4; ++kt) {
            half8 f;
            #pragma unroll
            for (int jj = 0; jj < 8; ++jj)
                f[jj] = (_Float16)We[(32 * kt + 8 * q + jj) * HDIM + wrcol];
            wef[kt] = f;
        }
        for (int t = 0; t < SEQ; ++t) {
            const _Float16* er = &S.ench[t][0][0] + ((l >> 2) & 1) * HPITCH + 8 * q;
            f32x4 dv = zeroq;
            #pragma unroll
            for (int kt = 0; kt < 4; ++kt) {
                half8 a = *(const half8*)(er + 32 * kt);
                dv = __builtin_amdgcn_mfma_f32_16x16x32_f16(a, wef[kt], dv, 0, 0, 0);
            }
            if (q < 2) S.encWe[t][q][wrcol] = (_Float16)dv[0];  // reg0 = row 4q = elem q
        }
    }

    // ---- decoder weights (pre-scaled) ----
    half8 wdf[4];
    #pragma unroll
    for (int g = 0; g < 4; ++g) {
        int n = g * HDIM + wrcol;
        float sc = gscale[g];
        wih[g] = Wih_d[n] * sc;
        bia[g] = b_d[n] * sc;
        #pragma unroll
        for (int kt = 0; kt < 4; ++kt) {
            half8 f;
            #pragma unroll
            for (int jj = 0; jj < 8; ++jj)
                f[jj] = (_Float16)(Whh_d[(32 * kt + 8 * q + jj) * G4 + n] * sc);
            whh[g][kt] = f;
        }
    }
    #pragma unroll
    for (int kt = 0; kt < 4; ++kt) {
        half8 f;
        #pragma unroll
        for (int jj = 0; jj < 8; ++jj)
            f[jj] = (_Float16)Wd[(32 * kt + 8 * q + jj) * HDIM + wrcol];
        wdf[kt] = f;
    }
    float bf0 = bfp[0];
    __syncthreads();   // encWe + x0 visible

    // ---- decoder: 8 steps, parity alternates (h enters in h2[0]) ----
    #pragma unroll 1
    for (int dd = 0; dd < TLEN; ++dd) {
        const bool even = (dd & 1) == 0;
        const _Float16* sC = even ? s0 : s1;
        const _Float16* sO = even ? s1 : s0;
        _Float16* dC = even ? d0 : d1;
        _Float16* dO = even ? d1 : d0;

        // hWd = h @ Wd
        {
            const _Float16* sp = sC + ((l >> 2) & 1) * HPITCH + 8 * q;
            half8 a0 = *(const half8*)(sp);
            half8 a1 = *(const half8*)(sp + 32);
            half8 a2 = *(const half8*)(sp + 64);
            half8 a3 = *(const half8*)(sp + 96);
            f32x4 dv = zeroq;
            dv = __builtin_amdgcn_mfma_f32_16x16x32_f16(a0, wdf[0], dv, 0, 0, 0);
            dv = __builtin_amdgcn_mfma_f32_16x16x32_f16(a1, wdf[1], dv, 0, 0, 0);
            dv = __builtin_amdgcn_mfma_f32_16x16x32_f16(a2, wdf[2], dv, 0, 0, 0);
            dv = __builtin_amdgcn_mfma_f32_16x16x32_f16(a3, wdf[3], dv, 0, 0, 0);
            if (q < 2) S.hWdh[q][wrcol] = (_Float16)dv[0];
        }
        __syncthreads();
        // scores
        if (tid < 2 * SEQ * 16) {
            int p = tid >> 4, sub = tid & 15;
            int m = p & 1, t = p >> 1;
            float s = 0.0f;
            #pragma unroll
            for (int i = 0; i < 8; ++i) {
                int j = sub * 8 + i;
                s = fmaf(ftanh_((float)S.encWe[t][m][j] + (float)S.hWdh[m][j]), S.wv[j], s);
            }
            s += __shfl_down(s, 8, 16);
            s += __shfl_down(s, 4, 16);
            s += __shfl_down(s, 2, 16);
            s += __shfl_down(s, 1, 16);
            if (sub == 0) S.score[m][t] = s;
        }
        __syncthreads();
        // softmax over 14 per element
        if (tid < 2) {
            int m = tid;
            float sc[SEQ]; float mx = -1e30f;
            #pragma unroll
            for (int t = 0; t < SEQ; ++t) { sc[t] = S.score[m][t]; mx = fmaxf(mx, sc[t]); }
            float ssum = 0.0f;
            #pragma unroll
            for (int t = 0; t < SEQ; ++t) { float e = __expf(sc[t] - mx); sc[t] = e; ssum += e; }
            float inv = frcp_(ssum);
            #pragma unroll
            for (int t = 0; t < SEQ; ++t) {
                float a = sc[t] * inv;
                S.attnw[m][t] = a;
                S.asum[m][t] += a;
            }
        }
        __syncthreads();
        // context -> ctx2[j][e]
        if (tid < 256) {
            int e = tid >> 7, j = tid & 127;
            float a = 0.0f;
            #pragma unroll
            for (int t = 0; t < SEQ; ++t)
                a = fmaf(S.attnw[e][t], (float)S.ench[t][e][j], a);
            S.ctx2[j][e] = a;
        }
        __syncthreads();

        // decoder LSTM: 129 steps = 64 static-parity pairs + 1; x prefetched
        const f32x2* xp = (const f32x2*)&S.ctx2[0][0];
        f32x2 xd = xp[0];
        #pragma unroll 1
        for (int s2 = 0; s2 < 64; ++s2) {
            (void)lstm_core(sC, dO, xd, zeroq, whh, wih, bia, c, q, l);
            xd = xp[2 * s2 + 1];           // issued before the barrier
            __syncthreads();
            (void)lstm_core(sO, dC, xd, zeroq, whh, wih, bia, c, q, l);
            xd = xp[2 * s2 + 2];           // s2=63 -> xp[128] = x row, valid
            __syncthreads();
        }
        (void)lstm_core(sC, dO, xd, zeroq, whh, wih, bia, c, q, l);
        __syncthreads();
        // h now in the "other" buffer; output projection -> next x
        const _Float16* hO = even ? &S.h2[1][0][0] : &S.h2[0][0][0];
        if (tid < 32) {
            int m = tid >> 4, part = tid & 15;
            half8 hv = *(const half8*)(hO + m * HPITCH + part * 8);
            float s = 0.0f;
            #pragma unroll
            for (int i = 0; i < 8; ++i) s = fmaf((float)hv[i], S.wf[part * 8 + i], s);
            s += __shfl_down(s, 8, 16);
            s += __shfl_down(s, 4, 16);
            s += __shfl_down(s, 2, 16);
            s += __shfl_down(s, 1, 16);
            if (part == 0) {
                float o = s + bf0;
                out[(b0 + m) * TLEN + dd] = o;
                S.ctx2[HDIM][m] = o;
            }
        }
        __syncthreads();
    }

    // total_attn [B, 14, 1]
    if (tid < 2 * SEQ) {
        int m = tid / SEQ, t = tid % SEQ;
        out[B * TLEN + (b0 + m) * SEQ + t] = S.asum[m][t];
    }
}

extern "C" void kernel_launch(void* const* d_in, const int* in_sizes, int n_in,
                              void* d_out, int out_size, void* d_ws, size_t ws_size,
                              hipStream_t stream) {
    const float* inputs = (const float*)d_in[0];
    const float* Wih_e = (const float*)d_in[2];
    const float* Whh_e = (const float*)d_in[3];
    const float* b_e   = (const float*)d_in[4];
    const float* Wih_d = (const float*)d_in[5];
    const float* Whh_d = (const float*)d_in[6];
    const float* b_d   = (const float*)d_in[7];
    const float* We    = (const float*)d_in[8];
    const float* Wd    = (const float*)d_in[9];
    const float* Wv    = (const float*)d_in[10];
    const float* Wf    = (const float*)d_in[11];
    const float* bfp   = (const float*)d_in[12];
    float* out = (float*)d_out;

    const int B = in_sizes[0] / SEQ;  // 512

    seq2seq_kernel<<<dim3(B / 2), dim3(NTHR), 0, stream>>>(
        inputs, Wih_e, Whh_e, b_e, Wih_d, Whh_d, b_d, We, Wd, Wv, Wf, bfp, out, B);
}